// Round 2
// baseline (389.789 us; speedup 1.0000x reference)
//
#include <hip/hip_runtime.h>
#include <hip/hip_fp16.h>
#include <math.h>

// Problem constants (match reference)
#define BB 8
#define NN 2048
#define NCH 64
#define LN_EPS 1e-5f
#define BN (BB * NN)
#define NBLK 512          // 2 blocks/CU on 256 CUs -> co-resident by construction

typedef float f4 __attribute__((ext_vector_type(4)));

// ---------------------------------------------------------------------------
// Grid-wide barrier from device-scope primitives (no cooperative launch).
// Monotone counter in ws (zeroed by hipMemsetAsync before launch, capture-safe).
// __threadfence() = agent-scope fence -> L2 writeback (release) / L2+L1
// invalidate (acquire) on gfx950, giving cross-XCD visibility.
// Bounded spin: a failure shows up as wrong results, never a hang.
// ---------------------------------------------------------------------------
__device__ __forceinline__ void grid_barrier(unsigned* bar, unsigned target) {
    __syncthreads();   // all waves' stores drained to L2 (vmcnt(0) before s_barrier)
    if (threadIdx.x == 0) {
        __threadfence();                        // release: write back our L2
        __hip_atomic_fetch_add(bar, 1u, __ATOMIC_ACQ_REL, __HIP_MEMORY_SCOPE_AGENT);
        int guard = 0;
        while (__hip_atomic_load(bar, __ATOMIC_ACQUIRE, __HIP_MEMORY_SCOPE_AGENT) < target) {
            __builtin_amdgcn_s_sleep(2);
            if (++guard > (1 << 20)) break;     // ~65 ms failsafe
        }
        __threadfence();                        // acquire: invalidate stale L1/L2
    }
    __syncthreads();
}

// ---------------------------------------------------------------------------
// Single fused kernel, 4 phases:
//   phase 0: P0 = rowsum(X)
//   phase 1: P1 = A @ P0 (fp32 A nontemporal) + emit A16 = fp16(A) (LLC-resident)
//   phase 2: P2 = A16 @ P1   (block re-reads the rows it wrote)
//   phase 3: P3 = A16 @ P2, fused combine + LayerNorm + tanh (h staged in LDS)
// 512 blocks x 256 threads; each block owns 32 rows of one batch.
// ---------------------------------------------------------------------------
__global__ __launch_bounds__(256, 2) void fused_all(
        const float* __restrict__ A,      // [B, N, N] fp32
        const float* __restrict__ X,      // [B, N, 64]
        const float* __restrict__ h,      // [4, 64, N]
        const float* __restrict__ gamma,  // [64]
        const float* __restrict__ beta,   // [64]
        float* __restrict__ out,          // [B, N, 64]
        float* __restrict__ P,            // ws: [3][B*N]
        __half* __restrict__ A16,         // ws: [B, N, N] fp16
        unsigned* __restrict__ bar) {     // ws: barrier counter (zeroed)
    __shared__ float4 p4[NN / 4];        // 8 KB : p vector for this batch
    __shared__ float  hs[32][NCH][4];    // 32 KB: h tile [node-in-tile][ch][term]

    const int tid  = threadIdx.x;
    const int wave = tid >> 6;
    const int lane = tid & 63;
    const int blk  = blockIdx.x;          // 0..511
    const int b    = blk >> 6;            // batch
    const int bx   = blk & 63;            // 32-row tile within batch

    // ---------------- phase 0: P0[b,n] = sum_c X[b,n,c] ---------------------
    #pragma unroll
    for (int s = 0; s < 2; ++s) {
        const int row = blk * 32 + s * 16 + (tid >> 4);   // global row b*NN+n
        const int q   = tid & 15;
        float4 x = ((const float4*)X)[(size_t)row * 16 + q];
        float v = x.x + x.y + x.z + x.w;
        v += __shfl_xor(v, 8, 64);
        v += __shfl_xor(v, 4, 64);
        v += __shfl_xor(v, 2, 64);
        v += __shfl_xor(v, 1, 64);
        if (q == 0) P[row] = v;
    }
    grid_barrier(bar, NBLK);

    // ---------------- phase 1: P1 = A @ P0, A16 = fp16(A) -------------------
    {
        const float4* src = (const float4*)(P + (size_t)b * NN);
        p4[tid]       = src[tid];
        p4[tid + 256] = src[tid + 256];
        __syncthreads();

        const float* Ab = A + (size_t)b * NN * NN;
        #pragma unroll
        for (int s = 0; s < 2; ++s) {
            const int m0 = bx * 32 + s * 16 + wave * 4;
            f4 buf[2][8];
            {   // prologue (nontemporal: keep fp32 A out of LLC)
                const f4* r = (const f4*)(Ab + (size_t)m0 * NN);
                #pragma unroll
                for (int j = 0; j < 8; ++j)
                    buf[0][j] = __builtin_nontemporal_load(&r[j * 64 + lane]);
            }
            #pragma unroll
            for (int i = 0; i < 4; ++i) {
                const int m = m0 + i;
                if (i < 3) {
                    const f4* rn = (const f4*)(Ab + (size_t)(m + 1) * NN);
                    #pragma unroll
                    for (int j = 0; j < 8; ++j)
                        buf[(i + 1) & 1][j] = __builtin_nontemporal_load(&rn[j * 64 + lane]);
                }
                float acc = 0.f;
                #pragma unroll
                for (int j = 0; j < 8; ++j) {
                    f4 x      = buf[i & 1][j];
                    float4 pv = p4[j * 64 + lane];
                    acc += x.x * pv.x + x.y * pv.y + x.z * pv.z + x.w * pv.w;
                }
                // A16 store: REGULAR (LLC residency for phases 2-3)
                float2* A16r = (float2*)(A16 + (size_t)b * NN * NN + (size_t)m * NN);
                #pragma unroll
                for (int j = 0; j < 8; ++j) {
                    union { float2 f2; __half2 h2[2]; } u;
                    u.h2[0] = __floats2half2_rn(buf[i & 1][j].x, buf[i & 1][j].y);
                    u.h2[1] = __floats2half2_rn(buf[i & 1][j].z, buf[i & 1][j].w);
                    A16r[j * 64 + lane] = u.f2;
                }
                #pragma unroll
                for (int off = 32; off > 0; off >>= 1)
                    acc += __shfl_down(acc, off, 64);
                if (lane == 0) P[BN + (size_t)b * NN + m] = acc;
            }
        }
    }
    grid_barrier(bar, 2 * NBLK);

    // ---------------- phase 2: P2 = A16 @ P1 --------------------------------
    {
        const float4* src = (const float4*)(P + BN + (size_t)b * NN);
        p4[tid]       = src[tid];
        p4[tid + 256] = src[tid + 256];
        __syncthreads();

        const __half* Ab = A16 + (size_t)b * NN * NN;
        #pragma unroll
        for (int s = 0; s < 2; ++s) {
            const int m0 = bx * 32 + s * 16 + wave * 4;
            float4 buf[2][4];
            {
                const float4* r = (const float4*)(Ab + (size_t)m0 * NN);
                #pragma unroll
                for (int j = 0; j < 4; ++j) buf[0][j] = r[j * 64 + lane];
            }
            #pragma unroll
            for (int i = 0; i < 4; ++i) {
                const int m = m0 + i;
                if (i < 3) {
                    const float4* rn = (const float4*)(Ab + (size_t)(m + 1) * NN);
                    #pragma unroll
                    for (int j = 0; j < 4; ++j) buf[(i + 1) & 1][j] = rn[j * 64 + lane];
                }
                float acc = 0.f;
                #pragma unroll
                for (int j = 0; j < 4; ++j) {
                    float4 pa = p4[2 * (j * 64 + lane)];
                    float4 pb = p4[2 * (j * 64 + lane) + 1];
                    const __half2* hx = (const __half2*)&buf[i & 1][j];
                    float2 f0 = __half22float2(hx[0]);
                    float2 f1 = __half22float2(hx[1]);
                    float2 f2 = __half22float2(hx[2]);
                    float2 f3 = __half22float2(hx[3]);
                    acc += f0.x * pa.x + f0.y * pa.y + f1.x * pa.z + f1.y * pa.w
                         + f2.x * pb.x + f2.y * pb.y + f3.x * pb.z + f3.y * pb.w;
                }
                #pragma unroll
                for (int off = 32; off > 0; off >>= 1)
                    acc += __shfl_down(acc, off, 64);
                if (lane == 0) P[2 * BN + (size_t)b * NN + m] = acc;
            }
        }
    }
    grid_barrier(bar, 3 * NBLK);

    // ---------------- phase 3: P3 = A16 @ P2 + combine + LN + tanh ----------
    {
        const float4* src = (const float4*)(P + 2 * BN + (size_t)b * NN);
        p4[tid]       = src[tid];
        p4[tid + 256] = src[tid + 256];

        // stage h tile coalesced: thread (term=wave, ch=lane) loads
        // h[wave][lane][bx*32 .. +32) and scatters into hs[node][ch][term].
        {
            const float4* hr =
                (const float4*)(h + ((size_t)(wave * NCH + lane)) * NN + bx * 32);
            #pragma unroll
            for (int k = 0; k < 8; ++k) {
                float4 hv = hr[k];
                hs[k * 4 + 0][lane][wave] = hv.x;
                hs[k * 4 + 1][lane][wave] = hv.y;
                hs[k * 4 + 2][lane][wave] = hv.z;
                hs[k * 4 + 3][lane][wave] = hv.w;
            }
        }
        __syncthreads();

        const float g  = gamma[lane];
        const float be = beta[lane];
        const __half* Ab = A16 + (size_t)b * NN * NN;
        #pragma unroll
        for (int s = 0; s < 2; ++s) {
            const int m0 = bx * 32 + s * 16 + wave * 4;
            float4 buf[2][4];
            {
                const float4* r = (const float4*)(Ab + (size_t)m0 * NN);
                #pragma unroll
                for (int j = 0; j < 4; ++j) buf[0][j] = r[j * 64 + lane];
            }
            #pragma unroll
            for (int i = 0; i < 4; ++i) {
                const int m = m0 + i;
                if (i < 3) {
                    const float4* rn = (const float4*)(Ab + (size_t)(m + 1) * NN);
                    #pragma unroll
                    for (int j = 0; j < 4; ++j) buf[(i + 1) & 1][j] = rn[j * 64 + lane];
                }
                const int idx  = b * NN + m;
                const float p0 = P[idx];
                const float p1 = P[BN + idx];

                float acc = 0.f;
                #pragma unroll
                for (int j = 0; j < 4; ++j) {
                    float4 pa = p4[2 * (j * 64 + lane)];
                    float4 pb = p4[2 * (j * 64 + lane) + 1];
                    const __half2* hx = (const __half2*)&buf[i & 1][j];
                    float2 f0 = __half22float2(hx[0]);
                    float2 f1 = __half22float2(hx[1]);
                    float2 f2 = __half22float2(hx[2]);
                    float2 f3 = __half22float2(hx[3]);
                    acc += f0.x * pa.x + f0.y * pa.y + f1.x * pa.z + f1.y * pa.w
                         + f2.x * pb.x + f2.y * pb.y + f3.x * pb.z + f3.y * pb.w;
                }
                #pragma unroll
                for (int off = 32; off > 0; off >>= 1)   // all lanes need p3
                    acc += __shfl_xor(acc, off, 64);
                const float p3 = acc;
                const float p2 = ((const float*)p4)[m];  // P2 from LDS

                const int  node = s * 16 + wave * 4 + i;
                const float4 hv = *(const float4*)&hs[node][lane][0];
                float y = hv.x * p0 + hv.y * p1 + hv.z * p2 + hv.w * p3;

                float sum = y;
                #pragma unroll
                for (int off = 32; off > 0; off >>= 1)
                    sum += __shfl_xor(sum, off, 64);
                const float mean = sum * (1.f / NCH);

                float d  = y - mean;
                float vs = d * d;
                #pragma unroll
                for (int off = 32; off > 0; off >>= 1)
                    vs += __shfl_xor(vs, off, 64);
                const float rstd = rsqrtf(vs * (1.f / NCH) + LN_EPS);

                __builtin_nontemporal_store(
                    tanhf(d * rstd * g + be),
                    &out[(size_t)idx * NCH + lane]);
            }
        }
    }
}

// ---------------------------------------------------------------------------
extern "C" void kernel_launch(void* const* d_in, const int* in_sizes, int n_in,
                              void* d_out, int out_size, void* d_ws, size_t ws_size,
                              hipStream_t stream) {
    const float* A     = (const float*)d_in[0];  // [B, N, N]
    const float* X     = (const float*)d_in[1];  // [B, N, 64]
    const float* h     = (const float*)d_in[2];  // [4, 64, N]
    const float* gamma = (const float*)d_in[3];  // [64]
    const float* beta  = (const float*)d_in[4];  // [64]
    float* out = (float*)d_out;                  // [B, N, 64]

    // ws layout: [0,256) barrier, [4K, 4K+768K) P[3][BN], [1M, 1M+64M) A16
    unsigned* bar = (unsigned*)d_ws;
    float*    P   = (float*)((char*)d_ws + 4096);
    __half*   A16 = (__half*)((char*)d_ws + (1u << 20));

    hipMemsetAsync(d_ws, 0, 256, stream);   // zero barrier counter (capture-safe)

    fused_all<<<dim3(NBLK), dim3(256), 0, stream>>>(
        A, X, h, gamma, beta, out, P, A16, bar);
}